// Round 3
// baseline (647.438 us; speedup 1.0000x reference)
//
#include <hip/hip_runtime.h>
#include <hip/hip_bf16.h>
#include <cstddef>

#define B_ 4
#define S_ 1024
#define E_ 1024
#define H_ 16
#define D_ 64
#define BH_ (B_*H_)

typedef __attribute__((ext_vector_type(8))) short short8;    // 8 bf16
typedef __attribute__((ext_vector_type(4))) float f32x4;
typedef __attribute__((ext_vector_type(4))) unsigned short us4;
typedef unsigned short u16;

__device__ inline u16 f2b(float x) {
    return __builtin_bit_cast(u16, __float2bfloat16(x));
}
__device__ inline float b2f(u16 u) {
    return __bfloat162float(__builtin_bit_cast(__hip_bfloat16, u));
}
__device__ inline void splitf(float x, u16& h, u16& l) {
    h = f2b(x); l = f2b(x - b2f(h));
}

__device__ inline void split_one(const float* __restrict__ in,
                                 u16* __restrict__ oh, u16* __restrict__ ol, int i)
{
    float4 v = ((const float4*)in)[i];
    us4 h, l;
    splitf(v.x, ((u16*)&h)[0], ((u16*)&l)[0]);
    splitf(v.y, ((u16*)&h)[1], ((u16*)&l)[1]);
    splitf(v.z, ((u16*)&h)[2], ((u16*)&l)[2]);
    splitf(v.w, ((u16*)&h)[3], ((u16*)&l)[3]);
    ((us4*)oh)[i] = h;
    ((us4*)ol)[i] = l;
}

__device__ inline void conv_one(const float* __restrict__ in,
                                u16* __restrict__ ob, int i)
{
    float4 v = ((const float4*)in)[i];
    us4 h;
    ((u16*)&h)[0] = f2b(v.x); ((u16*)&h)[1] = f2b(v.y);
    ((u16*)&h)[2] = f2b(v.z); ((u16*)&h)[3] = f2b(v.w);
    ((us4*)ob)[i] = h;
}

// ---------------------------------------------------------------------------
// Fused prep (unchanged, PASSING)
// ---------------------------------------------------------------------------
__global__ __launch_bounds__(256) void prep(
    const float* __restrict__ x, const float* __restrict__ W0,
    const float* __restrict__ W1, const float* __restrict__ Wv,
    const float* __restrict__ Wo, float* __restrict__ xsum_p,
    u16* __restrict__ xh, u16* __restrict__ xl,
    u16* __restrict__ w0h, u16* __restrict__ w0l,
    u16* __restrict__ w1h, u16* __restrict__ w1l,
    u16* __restrict__ wvb, u16* __restrict__ wob)
{
    int bid = blockIdx.x, tid = threadIdx.x;
    if (bid < 4096) {
        split_one(x, xh, xl, bid * 256 + tid);
    } else if (bid < 5120) {
        split_one(W0, w0h, w0l, (bid - 4096) * 256 + tid);
    } else if (bid < 6144) {
        split_one(W1, w1h, w1l, (bid - 5120) * 256 + tid);
    } else if (bid < 7168) {
        conv_one(Wv, wvb, (bid - 6144) * 256 + tid);
    } else if (bid < 8192) {
        conv_one(Wo, wob, (bid - 7168) * 256 + tid);
    } else {
        int p = bid - 8192;                 // [0,256)
        int kb = p & 3, b = (p >> 2) & 3, ch = p >> 4;
        int k = kb * 256 + tid;
        const float* base = x + ((size_t)(b * S_ + ch * 64)) * E_ + k;
        float s = 0.f;
#pragma unroll 8
        for (int j = 0; j < 64; ++j) s += base[(size_t)j * E_];
        xsum_p[(ch * 4 + b) * E_ + k] = s;
    }
}

// ---------------------------------------------------------------------------
// Fused t2 + M (unchanged, PASSING)
// ---------------------------------------------------------------------------
__global__ __launch_bounds__(256) void t2k_M(
    const float* __restrict__ W2, const float* __restrict__ b2v,
    const float* __restrict__ xsum_p, const float* __restrict__ A,
    u16* __restrict__ MTh, u16* __restrict__ MTl)
{
    int h = blockIdx.x, b = blockIdx.y, tid = threadIdx.x;
    __shared__ float xs[1024];
    __shared__ float t2s[64];

#pragma unroll
    for (int j = 0; j < 4; ++j) {
        int k = j * 256 + tid;
        float s = 0.f;
#pragma unroll
        for (int c = 0; c < 16; ++c) s += xsum_p[(c * 4 + b) * E_ + k];
        xs[k] = s;
    }
    __syncthreads();

    int w = tid >> 6, lane = tid & 63;
    for (int nn = w; nn < 64; nn += 4) {
        int n = h * 64 + nn;
        const float* wr = W2 + (size_t)n * E_;
        float s = 0.f;
#pragma unroll
        for (int t = 0; t < 16; ++t) s = fmaf(wr[t * 64 + lane], xs[t * 64 + lane], s);
#pragma unroll
        for (int off = 1; off < 64; off <<= 1) s += __shfl_xor(s, off, 64);
        if (lane == 0) t2s[nn] = s + 1024.0f * b2v[n];
    }
    __syncthreads();

    int bh = b * H_ + h;
    int c = tid & 63;
    int a0 = (tid >> 6) * 16;
    for (int a = a0; a < a0 + 16; ++a) {
        float s = 0.f;
        const float* Ap = A + ((size_t)a * 64 + c) * 64;
#pragma unroll 8
        for (int d = 0; d < 64; ++d) s = fmaf(Ap[d], t2s[d], s);
        u16 hh, ll; splitf(s * 0.125f, hh, ll);
        MTh[(size_t)bh * 4096 + c * 64 + a] = hh;
        MTl[(size_t)bh * 4096 + c * 64 + a] = ll;
    }
}

// ---------------------------------------------------------------------------
// qp1 body: split GEMM 128x64 (verbatim R2, PASSING)
// ---------------------------------------------------------------------------
__device__ void qp1_body(
    const u16* __restrict__ Xh, const u16* __restrict__ Xl,
    const u16* __restrict__ W0h_, const u16* __restrict__ W0l_,
    const u16* __restrict__ W1h_, const u16* __restrict__ W1l_,
    const float* __restrict__ bias0, const float* __restrict__ bias1,
    const u16* __restrict__ MTh, const u16* __restrict__ MTl,
    u16* __restrict__ qh, u16* __restrict__ ql,
    u16* __restrict__ p1h, u16* __restrict__ p1l,
    int bm, int bn, char* smem)
{
    const int K = 1024;
    u16* Xs_h  = (u16*)smem;             // 128*40
    u16* Xs_l  = Xs_h + 128 * 40;
    u16* W0s_h = Xs_l + 128 * 40;        // 64*40 each
    u16* W0s_l = W0s_h + 64 * 40;
    u16* W1s_h = W0s_l + 64 * 40;
    u16* W1s_l = W1s_h + 64 * 40;        // staging total 40960 B
    u16* Cs_h  = (u16*)smem;             // epilogue: 128*72
    u16* Cs_l  = Cs_h + 128 * 72;        // 36864 B (alias)

    const int tid = threadIdx.x;
    const int w = tid >> 6, lane = tid & 63;
    const int waveM = w & 1, waveN = w >> 1;
    const int quad = lane >> 4, l16 = lane & 15;

    const int xrow = tid >> 1, xko = (tid & 1) * 16;
    const int wrow = tid >> 2, wko = (tid & 3) * 8;

    const u16* xh_g  = Xh  + (size_t)(bm * 128 + xrow) * K + xko;
    const u16* xl_g  = Xl  + (size_t)(bm * 128 + xrow) * K + xko;
    const u16* w0h_g = W0h_ + (size_t)(bn * 64 + wrow) * K + wko;
    const u16* w0l_g = W0l_ + (size_t)(bn * 64 + wrow) * K + wko;
    const u16* w1h_g = W1h_ + (size_t)(bn * 64 + wrow) * K + wko;
    const u16* w1l_g = W1l_ + (size_t)(bn * 64 + wrow) * K + wko;

    f32x4 acc0[4][2] = {};
    f32x4 acc1[4][2] = {};

    for (int k0 = 0; k0 < K; k0 += 32) {
        uint4 xa = *(const uint4*)(xh_g + k0);
        uint4 xb = *(const uint4*)(xh_g + k0 + 8);
        uint4 xc = *(const uint4*)(xl_g + k0);
        uint4 xd = *(const uint4*)(xl_g + k0 + 8);
        uint4 w0a = *(const uint4*)(w0h_g + k0);
        uint4 w0c = *(const uint4*)(w0l_g + k0);
        uint4 w1a = *(const uint4*)(w1h_g + k0);
        uint4 w1c = *(const uint4*)(w1l_g + k0);
        __syncthreads();
        *(uint4*)&Xs_h[xrow * 40 + xko]     = xa;
        *(uint4*)&Xs_h[xrow * 40 + xko + 8] = xb;
        *(uint4*)&Xs_l[xrow * 40 + xko]     = xc;
        *(uint4*)&Xs_l[xrow * 40 + xko + 8] = xd;
        *(uint4*)&W0s_h[wrow * 40 + wko] = w0a;
        *(uint4*)&W0s_l[wrow * 40 + wko] = w0c;
        *(uint4*)&W1s_h[wrow * 40 + wko] = w1a;
        *(uint4*)&W1s_l[wrow * 40 + wko] = w1c;
        __syncthreads();

        short8 ah[4], al[4], b0h[2], b0l[2], b1h[2], b1l[2];
#pragma unroll
        for (int mt = 0; mt < 4; ++mt) {
            int r = (waveM * 64 + mt * 16 + l16) * 40 + quad * 8;
            ah[mt] = *(short8*)&Xs_h[r];
            al[mt] = *(short8*)&Xs_l[r];
        }
#pragma unroll
        for (int nt = 0; nt < 2; ++nt) {
            int r = (waveN * 32 + nt * 16 + l16) * 40 + quad * 8;
            b0h[nt] = *(short8*)&W0s_h[r];
            b0l[nt] = *(short8*)&W0s_l[r];
            b1h[nt] = *(short8*)&W1s_h[r];
            b1l[nt] = *(short8*)&W1s_l[r];
        }
#pragma unroll
        for (int mt = 0; mt < 4; ++mt)
#pragma unroll
            for (int nt = 0; nt < 2; ++nt) {
                acc0[mt][nt] = __builtin_amdgcn_mfma_f32_16x16x32_bf16(ah[mt], b0h[nt], acc0[mt][nt], 0, 0, 0);
                acc1[mt][nt] = __builtin_amdgcn_mfma_f32_16x16x32_bf16(ah[mt], b1h[nt], acc1[mt][nt], 0, 0, 0);
                acc0[mt][nt] = __builtin_amdgcn_mfma_f32_16x16x32_bf16(ah[mt], b0l[nt], acc0[mt][nt], 0, 0, 0);
                acc1[mt][nt] = __builtin_amdgcn_mfma_f32_16x16x32_bf16(ah[mt], b1l[nt], acc1[mt][nt], 0, 0, 0);
                acc0[mt][nt] = __builtin_amdgcn_mfma_f32_16x16x32_bf16(al[mt], b0h[nt], acc0[mt][nt], 0, 0, 0);
                acc1[mt][nt] = __builtin_amdgcn_mfma_f32_16x16x32_bf16(al[mt], b1h[nt], acc1[mt][nt], 0, 0, 0);
            }
    }

    const int bh = (bm >> 3) * H_ + bn;   // 8 m-blocks per batch; head = bn

    // ---- p1 epilogue (no LDS) ----
#pragma unroll
    for (int mt = 0; mt < 4; ++mt)
#pragma unroll
        for (int nt = 0; nt < 2; ++nt)
#pragma unroll
            for (int r = 0; r < 4; ++r) {
                int m = bm * 128 + waveM * 64 + mt * 16 + quad * 4 + r;
                int n = bn * 64 + waveN * 32 + nt * 16 + l16;
                float val = acc1[mt][nt][r] + bias1[n];
                int s = m & 1023, c = n & 63;
                size_t addr = ((size_t)bh * S_ + s) * 64 + c;
                u16 hh, ll; splitf(val, hh, ll);
                p1h[addr] = hh; p1l[addr] = ll;
            }

    // ---- q epilogue: q = (acc0 + b0) @ M_bh via split MFMA ----
    __syncthreads();
#pragma unroll
    for (int mt = 0; mt < 4; ++mt)
#pragma unroll
        for (int nt = 0; nt < 2; ++nt)
#pragma unroll
            for (int r = 0; r < 4; ++r) {
                int i = waveM * 64 + mt * 16 + quad * 4 + r;
                int a = waveN * 32 + nt * 16 + l16;
                float val = acc0[mt][nt][r] + bias0[bn * 64 + a];
                u16 hh, ll; splitf(val, hh, ll);
                Cs_h[i * 72 + a] = hh;
                Cs_l[i * 72 + a] = ll;
            }
    __syncthreads();

    const u16* MTh_b = MTh + (size_t)bh * 4096;
    const u16* MTl_b = MTl + (size_t)bh * 4096;
    f32x4 qacc[4][2] = {};
#pragma unroll
    for (int ch = 0; ch < 2; ++ch) {
        short8 mh[2], ml[2];
#pragma unroll
        for (int nt = 0; nt < 2; ++nt) {
            int c = waveN * 32 + nt * 16 + l16;
            mh[nt] = *(const short8*)&MTh_b[c * 64 + ch * 32 + quad * 8];
            ml[nt] = *(const short8*)&MTl_b[c * 64 + ch * 32 + quad * 8];
        }
#pragma unroll
        for (int mt = 0; mt < 4; ++mt) {
            int rr = (waveM * 64 + mt * 16 + l16) * 72 + ch * 32 + quad * 8;
            short8 ca = *(short8*)&Cs_h[rr];
            short8 cl = *(short8*)&Cs_l[rr];
#pragma unroll
            for (int nt = 0; nt < 2; ++nt) {
                qacc[mt][nt] = __builtin_amdgcn_mfma_f32_16x16x32_bf16(ca, mh[nt], qacc[mt][nt], 0, 0, 0);
                qacc[mt][nt] = __builtin_amdgcn_mfma_f32_16x16x32_bf16(ca, ml[nt], qacc[mt][nt], 0, 0, 0);
                qacc[mt][nt] = __builtin_amdgcn_mfma_f32_16x16x32_bf16(cl, mh[nt], qacc[mt][nt], 0, 0, 0);
            }
        }
    }
#pragma unroll
    for (int mt = 0; mt < 4; ++mt)
#pragma unroll
        for (int nt = 0; nt < 2; ++nt)
#pragma unroll
            for (int r = 0; r < 4; ++r) {
                int s = (bm & 7) * 128 + waveM * 64 + mt * 16 + quad * 4 + r;
                int c = waveN * 32 + nt * 16 + l16;
                size_t addr = ((size_t)bh * S_ + s) * 64 + c;
                u16 hh, ll; splitf(qacc[mt][nt][r], hh, ll);
                qh[addr] = hh; ql[addr] = ll;
            }
}

// ---------------------------------------------------------------------------
// plain bf16 GEMM body, 128x64 tile (verbatim R2, PASSING)
// ---------------------------------------------------------------------------
__device__ void plain128_body(
    const u16* __restrict__ Xb, const u16* __restrict__ Wb,
    const float* __restrict__ bias, u16* __restrict__ outB,
    float* __restrict__ outF, int mode, int bm, int bn, char* smem)
{
    const int K = 1024;
    u16* Xs = (u16*)smem;                // 128*40
    u16* Ws = Xs + 128 * 40;             // 64*40  (total 15360 B)

    const int tid = threadIdx.x;
    const int w = tid >> 6, lane = tid & 63;
    const int waveM = w & 1, waveN = w >> 1;
    const int quad = lane >> 4, l16 = lane & 15;
    const int xrow = tid >> 1, xko = (tid & 1) * 16;
    const int wrow = tid >> 2, wko = (tid & 3) * 8;

    const u16* xg = Xb + (size_t)(bm * 128 + xrow) * K + xko;
    const u16* wg = Wb + (size_t)(bn * 64 + wrow) * K + wko;

    f32x4 acc[4][2] = {};

    for (int k0 = 0; k0 < K; k0 += 32) {
        uint4 xa = *(const uint4*)(xg + k0);
        uint4 xb = *(const uint4*)(xg + k0 + 8);
        uint4 wa = *(const uint4*)(wg + k0);
        __syncthreads();
        *(uint4*)&Xs[xrow * 40 + xko]     = xa;
        *(uint4*)&Xs[xrow * 40 + xko + 8] = xb;
        *(uint4*)&Ws[wrow * 40 + wko]     = wa;
        __syncthreads();

        short8 af[4], bf_[2];
#pragma unroll
        for (int mt = 0; mt < 4; ++mt)
            af[mt] = *(short8*)&Xs[(waveM * 64 + mt * 16 + l16) * 40 + quad * 8];
#pragma unroll
        for (int nt = 0; nt < 2; ++nt)
            bf_[nt] = *(short8*)&Ws[(waveN * 32 + nt * 16 + l16) * 40 + quad * 8];
#pragma unroll
        for (int mt = 0; mt < 4; ++mt)
#pragma unroll
            for (int nt = 0; nt < 2; ++nt)
                acc[mt][nt] = __builtin_amdgcn_mfma_f32_16x16x32_bf16(af[mt], bf_[nt], acc[mt][nt], 0, 0, 0);
    }

#pragma unroll
    for (int mt = 0; mt < 4; ++mt)
#pragma unroll
        for (int nt = 0; nt < 2; ++nt)
#pragma unroll
            for (int r = 0; r < 4; ++r) {
                int m = bm * 128 + waveM * 64 + mt * 16 + quad * 4 + r;
                int n = bn * 64 + waveN * 32 + nt * 16 + l16;
                float val = acc[mt][nt][r] + bias[n];
                if (mode == 0) {
                    int b = m >> 10, s = m & 1023, h = n >> 6, c = n & 63;
                    outB[((size_t)((b * H_ + h) * 64 + c)) * S_ + s] = f2b(val);
                } else {
                    outF[(size_t)m * 1024 + n] = val;
                }
            }
}

// ---------------------------------------------------------------------------
// merged mid kernel (verbatim R2)
// ---------------------------------------------------------------------------
__global__ __launch_bounds__(256) void gemm_mid(
    const u16* __restrict__ xh, const u16* __restrict__ xl,
    const u16* __restrict__ w0h, const u16* __restrict__ w0l,
    const u16* __restrict__ w1h, const u16* __restrict__ w1l,
    const float* __restrict__ b0, const float* __restrict__ b1,
    const u16* __restrict__ MTh, const u16* __restrict__ MTl,
    u16* __restrict__ qh, u16* __restrict__ ql,
    u16* __restrict__ p1h, u16* __restrict__ p1l,
    const u16* __restrict__ wvb, const float* __restrict__ bv,
    u16* __restrict__ vT)
{
    __shared__ __align__(16) char smem[40960];
    int bid = blockIdx.x;
    if (bid < 512) {
        qp1_body(xh, xl, w0h, w0l, w1h, w1l, b0, b1, MTh, MTl,
                 qh, ql, p1h, p1l, bid & 31, bid >> 5, smem);
    } else {
        int b2 = bid - 512;
        plain128_body(xh, wvb, bv, vT, nullptr, 0, b2 & 31, b2 >> 5, smem);
    }
}

// final GEMM: out = values @ Wo^T + bo (fp32 out)
__global__ __launch_bounds__(256) void gemm_fin(
    const u16* __restrict__ values, const u16* __restrict__ wob,
    const float* __restrict__ bo, float* __restrict__ out)
{
    __shared__ __align__(16) char smem[15360];
    plain128_body(values, wob, bo, nullptr, out, 1, blockIdx.x, blockIdx.y, smem);
}

// ---------------------------------------------------------------------------
// FUSED logits+softmax+PV, restructured:
//  - q A-frags direct from global (no q LDS stage, no barrier)
//  - QK B-frags direct from global (L2-resident per bh via XCD swizzle) —
//    no p1 LDS staging, ZERO barriers in the QK loop
//  - P (32x1024 bf16) written ONCE to 64KB LDS with XOR swizzle
//    off ^= (row&7)<<4  (conflict-free b128 reads at row stride 2048B)
//  - PV: A-frags from swizzled LDS, V-frags direct from global — barrier-free
// Barriers: 26 -> 4. MFMA order per output unchanged (bitwise identical).
// redm/reds alias the P region (only live between softmax barriers).
// ---------------------------------------------------------------------------
__global__ __launch_bounds__(512) void logits_softmax_pv(
    const u16* __restrict__ qh, const u16* __restrict__ ql,
    const u16* __restrict__ p1h, const u16* __restrict__ p1l,
    const u16* __restrict__ vT, float* __restrict__ attn,
    u16* __restrict__ values)
{
    int bh = blockIdx.x, i0 = blockIdx.y * 32;
    int b = bh >> 4, h = bh & 15;
    int tid = threadIdx.x, w = tid >> 6, lane = tid & 63;
    int quad = lane >> 4, l16 = lane & 15;
    int wg = w >> 2, wj = w & 3;

    __shared__ __align__(16) char sm[65536];  // P [32][2048B] swizzled
    float* redm = (float*)sm;                 // [4][32] alias (softmax window)
    float* reds = (float*)(sm + 512);

    // ---- q A-frags direct from global ----
    short8 ah[2], al[2];
    {
        size_t gq = ((size_t)bh * S_ + i0 + wg * 16 + l16) * 64 + quad * 8;
        ah[0] = *(const short8*)&qh[gq];
        ah[1] = *(const short8*)&qh[gq + 32];
        al[0] = *(const short8*)&ql[gq];
        al[1] = *(const short8*)&ql[gq + 32];
    }

    // ---- QK: B-frags direct from global, barrier-free ----
    const size_t gpb = ((size_t)bh * S_ + wj * 16 + l16) * 64 + quad * 8;
    f32x4 L[16];
#pragma unroll
    for (int t = 0; t < 16; ++t) {
        size_t g = gpb + (size_t)t * 4096;
        short8 bh0 = *(const short8*)&p1h[g];
        short8 bh1 = *(const short8*)&p1h[g + 32];
        short8 bl0 = *(const short8*)&p1l[g];
        short8 bl1 = *(const short8*)&p1l[g + 32];
        f32x4 a = {};
        a = __builtin_amdgcn_mfma_f32_16x16x32_bf16(ah[0], bh0, a, 0, 0, 0);
        a = __builtin_amdgcn_mfma_f32_16x16x32_bf16(ah[1], bh1, a, 0, 0, 0);
        a = __builtin_amdgcn_mfma_f32_16x16x32_bf16(ah[0], bl0, a, 0, 0, 0);
        a = __builtin_amdgcn_mfma_f32_16x16x32_bf16(ah[1], bl1, a, 0, 0, 0);
        a = __builtin_amdgcn_mfma_f32_16x16x32_bf16(al[0], bh0, a, 0, 0, 0);
        a = __builtin_amdgcn_mfma_f32_16x16x32_bf16(al[1], bh1, a, 0, 0, 0);
        L[t] = a;
    }

    // ---- softmax (structure unchanged) ----
    float mrow[4], srow[4];
#pragma unroll
    for (int r = 0; r < 4; ++r) {
        float m = L[0][r];
#pragma unroll
        for (int t = 1; t < 16; ++t) m = fmaxf(m, L[t][r]);
#pragma unroll
        for (int off = 1; off < 16; off <<= 1) m = fmaxf(m, __shfl_xor(m, off, 64));
        mrow[r] = m;
    }
    if (l16 == 0)
#pragma unroll
        for (int r = 0; r < 4; ++r) redm[wj * 32 + wg * 16 + quad * 4 + r] = mrow[r];
    __syncthreads();
#pragma unroll
    for (int r = 0; r < 4; ++r) {
        int rowg = wg * 16 + quad * 4 + r;
        float m = fmaxf(fmaxf(redm[0 * 32 + rowg], redm[1 * 32 + rowg]),
                        fmaxf(redm[2 * 32 + rowg], redm[3 * 32 + rowg]));
        float s = 0.f;
#pragma unroll
        for (int t = 0; t < 16; ++t) { L[t][r] = __expf(L[t][r] - m); s += L[t][r]; }
#pragma unroll
        for (int off = 1; off < 16; off <<= 1) s += __shfl_xor(s, off, 64);
        srow[r] = s;
    }
    if (l16 == 0)
#pragma unroll
        for (int r = 0; r < 4; ++r) reds[wj * 32 + wg * 16 + quad * 4 + r] = srow[r];
    __syncthreads();
#pragma unroll
    for (int r = 0; r < 4; ++r) {
        int rowg = wg * 16 + quad * 4 + r;
        float inv = 1.0f / (reds[0 * 32 + rowg] + reds[1 * 32 + rowg] +
                            reds[2 * 32 + rowg] + reds[3 * 32 + rowg]);
        float* arow = attn + ((size_t)bh * S_ + i0 + rowg) * S_;
#pragma unroll
        for (int t = 0; t < 16; ++t) {
            float p = L[t][r] * inv;
            L[t][r] = p;
            __builtin_nontemporal_store(p, &arow[t * 64 + wj * 16 + l16]);
        }
    }

    // ---- fence reds reads, then write whole P to swizzled LDS ----
    __syncthreads();
    {
        int row = wg * 16 + quad * 4;
        int colb = (wj * 16 + l16) * 2;
#pragma unroll
        for (int t = 0; t < 16; ++t)
#pragma unroll
            for (int r = 0; r < 4; ++r) {
                int off = (t * 128 + colb) ^ (((row + r) & 7) << 4);
                *(u16*)(sm + (row + r) * 2048 + off) = f2b(L[t][r]);
            }
    }
    __syncthreads();

    // ---- PV: P from swizzled LDS, V direct from global, barrier-free ----
    const int d = wj * 16 + l16;
    const int arow = wg * 16 + l16;
    const char* Pr = sm + arow * 2048;
    const int rxor = (arow & 7) << 4;
    const size_t gvb = (size_t)(bh * 64 + d) * S_ + quad * 8;
    f32x4 acc_pv = {};
#pragma unroll
    for (int t = 0; t < 16; ++t)
#pragma unroll
        for (int cc = 0; cc < 64; cc += 32) {
            short8 af = *(const short8*)(Pr + ((t * 128 + cc * 2 + quad * 16) ^ rxor));
            short8 bf = *(const short8*)&vT[gvb + t * 64 + cc];
            acc_pv = __builtin_amdgcn_mfma_f32_16x16x32_bf16(af, bf, acc_pv, 0, 0, 0);
        }
#pragma unroll
    for (int r = 0; r < 4; ++r) {
        int i = i0 + wg * 16 + quad * 4 + r;
        values[((size_t)(b * S_ + i)) * E_ + h * 64 + d] = f2b(acc_pv[r]);
    }
}

extern "C" void kernel_launch(void* const* d_in, const int* in_sizes, int n_in,
                              void* d_out, int out_size, void* d_ws, size_t ws_size,
                              hipStream_t stream)
{
    const float* x  = (const float*)d_in[0];
    const float* W0 = (const float*)d_in[1];
    const float* b0 = (const float*)d_in[2];
    const float* W1 = (const float*)d_in[3];
    const float* b1 = (const float*)d_in[4];
    const float* W2 = (const float*)d_in[5];
    const float* b2 = (const float*)d_in[6];
    const float* Wv = (const float*)d_in[7];
    const float* bv = (const float*)d_in[8];
    const float* Wo = (const float*)d_in[9];
    const float* bo = (const float*)d_in[10];
    const float* A  = (const float*)d_in[11];

    float* out  = (float*)d_out;
    float* attn = out + (size_t)B_ * S_ * E_;

    // workspace (~78.6 MB)
    u16* xh  = (u16*)d_ws;                  // 8 MB
    u16* xl  = xh + 4194304;                // 8 MB
    u16* w0h = xl + 4194304;                // 2 MB
    u16* w0l = w0h + 1048576;
    u16* w1h = w0l + 1048576;
    u16* w1l = w1h + 1048576;
    u16* p1h = w1l + 1048576;               // 8 MB
    u16* p1l = p1h + 4194304;               // 8 MB
    u16* qh  = p1l + 4194304;               // 8 MB
    u16* ql  = qh + 4194304;                // 8 MB
    u16* vT  = ql + 4194304;                // 8 MB (heads-transposed v)
    u16* values = vT + 4194304;             // 8 MB (bf16 natural)
    u16* MTh = values + 4194304;            // 512 KB (transposed M hi)
    u16* MTl = MTh + 262144;                // 512 KB
    u16* wob = MTl + 262144;                // 2 MB (bf16 Wo)
    // xsum partials [16][4][1024] fp32 = 256 KB — aliased onto p1h (written
    // by gemm_mid strictly after t2k_M consumed xsum_p).
    float* xsum_p = (float*)p1h;
    // wvb aliased onto values region: consumed by gemm_mid, which completes
    // before logits_softmax_pv writes values.
    u16* wvb = values;

    prep<<<8448, 256, 0, stream>>>(x, W0, W1, Wv, Wo, xsum_p,
                                   xh, xl, w0h, w0l, w1h, w1l, wvb, wob);
    t2k_M<<<dim3(16, 4), 256, 0, stream>>>(W2, b2, xsum_p, A, MTh, MTl);

    gemm_mid<<<1024, 256, 0, stream>>>(xh, xl, w0h, w0l, w1h, w1l,
                                       b0, b1, MTh, MTl, qh, ql, p1h, p1l,
                                       wvb, bv, vT);

    logits_softmax_pv<<<dim3(64, 32), 512, 0, stream>>>(qh, ql, p1h, p1l, vT, attn, values);

    gemm_fin<<<dim3(32, 16), 256, 0, stream>>>(values, wob, bo, out);
}

// Round 4
// 593.047 us; speedup vs baseline: 1.0917x; 1.0917x over previous
//
#include <hip/hip_runtime.h>
#include <hip/hip_bf16.h>
#include <cstddef>

#define B_ 4
#define S_ 1024
#define E_ 1024
#define H_ 16
#define D_ 64
#define BH_ (B_*H_)

typedef __attribute__((ext_vector_type(8))) short short8;    // 8 bf16
typedef __attribute__((ext_vector_type(4))) float f32x4;
typedef __attribute__((ext_vector_type(4))) unsigned short us4;
typedef unsigned short u16;

__device__ inline u16 f2b(float x) {
    return __builtin_bit_cast(u16, __float2bfloat16(x));
}
__device__ inline float b2f(u16 u) {
    return __bfloat162float(__builtin_bit_cast(__hip_bfloat16, u));
}
__device__ inline void splitf(float x, u16& h, u16& l) {
    h = f2b(x); l = f2b(x - b2f(h));
}

__device__ inline void split_one(const float* __restrict__ in,
                                 u16* __restrict__ oh, u16* __restrict__ ol, int i)
{
    float4 v = ((const float4*)in)[i];
    us4 h, l;
    splitf(v.x, ((u16*)&h)[0], ((u16*)&l)[0]);
    splitf(v.y, ((u16*)&h)[1], ((u16*)&l)[1]);
    splitf(v.z, ((u16*)&h)[2], ((u16*)&l)[2]);
    splitf(v.w, ((u16*)&h)[3], ((u16*)&l)[3]);
    ((us4*)oh)[i] = h;
    ((us4*)ol)[i] = l;
}

__device__ inline void conv_one(const float* __restrict__ in,
                                u16* __restrict__ ob, int i)
{
    float4 v = ((const float4*)in)[i];
    us4 h;
    ((u16*)&h)[0] = f2b(v.x); ((u16*)&h)[1] = f2b(v.y);
    ((u16*)&h)[2] = f2b(v.z); ((u16*)&h)[3] = f2b(v.w);
    ((us4*)ob)[i] = h;
}

// ---------------------------------------------------------------------------
// Fused prep (unchanged, PASSING)
// ---------------------------------------------------------------------------
__global__ __launch_bounds__(256) void prep(
    const float* __restrict__ x, const float* __restrict__ W0,
    const float* __restrict__ W1, const float* __restrict__ Wv,
    const float* __restrict__ Wo, float* __restrict__ xsum_p,
    u16* __restrict__ xh, u16* __restrict__ xl,
    u16* __restrict__ w0h, u16* __restrict__ w0l,
    u16* __restrict__ w1h, u16* __restrict__ w1l,
    u16* __restrict__ wvb, u16* __restrict__ wob)
{
    int bid = blockIdx.x, tid = threadIdx.x;
    if (bid < 4096) {
        split_one(x, xh, xl, bid * 256 + tid);
    } else if (bid < 5120) {
        split_one(W0, w0h, w0l, (bid - 4096) * 256 + tid);
    } else if (bid < 6144) {
        split_one(W1, w1h, w1l, (bid - 5120) * 256 + tid);
    } else if (bid < 7168) {
        conv_one(Wv, wvb, (bid - 6144) * 256 + tid);
    } else if (bid < 8192) {
        conv_one(Wo, wob, (bid - 7168) * 256 + tid);
    } else {
        int p = bid - 8192;                 // [0,256)
        int kb = p & 3, b = (p >> 2) & 3, ch = p >> 4;
        int k = kb * 256 + tid;
        const float* base = x + ((size_t)(b * S_ + ch * 64)) * E_ + k;
        float s = 0.f;
#pragma unroll 8
        for (int j = 0; j < 64; ++j) s += base[(size_t)j * E_];
        xsum_p[(ch * 4 + b) * E_ + k] = s;
    }
}

// ---------------------------------------------------------------------------
// Fused t2 + M (unchanged, PASSING)
// ---------------------------------------------------------------------------
__global__ __launch_bounds__(256) void t2k_M(
    const float* __restrict__ W2, const float* __restrict__ b2v,
    const float* __restrict__ xsum_p, const float* __restrict__ A,
    u16* __restrict__ MTh, u16* __restrict__ MTl)
{
    int h = blockIdx.x, b = blockIdx.y, tid = threadIdx.x;
    __shared__ float xs[1024];
    __shared__ float t2s[64];

#pragma unroll
    for (int j = 0; j < 4; ++j) {
        int k = j * 256 + tid;
        float s = 0.f;
#pragma unroll
        for (int c = 0; c < 16; ++c) s += xsum_p[(c * 4 + b) * E_ + k];
        xs[k] = s;
    }
    __syncthreads();

    int w = tid >> 6, lane = tid & 63;
    for (int nn = w; nn < 64; nn += 4) {
        int n = h * 64 + nn;
        const float* wr = W2 + (size_t)n * E_;
        float s = 0.f;
#pragma unroll
        for (int t = 0; t < 16; ++t) s = fmaf(wr[t * 64 + lane], xs[t * 64 + lane], s);
#pragma unroll
        for (int off = 1; off < 64; off <<= 1) s += __shfl_xor(s, off, 64);
        if (lane == 0) t2s[nn] = s + 1024.0f * b2v[n];
    }
    __syncthreads();

    int bh = b * H_ + h;
    int c = tid & 63;
    int a0 = (tid >> 6) * 16;
    for (int a = a0; a < a0 + 16; ++a) {
        float s = 0.f;
        const float* Ap = A + ((size_t)a * 64 + c) * 64;
#pragma unroll 8
        for (int d = 0; d < 64; ++d) s = fmaf(Ap[d], t2s[d], s);
        u16 hh, ll; splitf(s * 0.125f, hh, ll);
        MTh[(size_t)bh * 4096 + c * 64 + a] = hh;
        MTl[(size_t)bh * 4096 + c * 64 + a] = ll;
    }
}

// ---------------------------------------------------------------------------
// qp1 body: split GEMM 128x64 (verbatim R2, PASSING)
// ---------------------------------------------------------------------------
__device__ void qp1_body(
    const u16* __restrict__ Xh, const u16* __restrict__ Xl,
    const u16* __restrict__ W0h_, const u16* __restrict__ W0l_,
    const u16* __restrict__ W1h_, const u16* __restrict__ W1l_,
    const float* __restrict__ bias0, const float* __restrict__ bias1,
    const u16* __restrict__ MTh, const u16* __restrict__ MTl,
    u16* __restrict__ qh, u16* __restrict__ ql,
    u16* __restrict__ p1h, u16* __restrict__ p1l,
    int bm, int bn, char* smem)
{
    const int K = 1024;
    u16* Xs_h  = (u16*)smem;             // 128*40
    u16* Xs_l  = Xs_h + 128 * 40;
    u16* W0s_h = Xs_l + 128 * 40;        // 64*40 each
    u16* W0s_l = W0s_h + 64 * 40;
    u16* W1s_h = W0s_l + 64 * 40;
    u16* W1s_l = W1s_h + 64 * 40;        // staging total 40960 B
    u16* Cs_h  = (u16*)smem;             // epilogue: 128*72
    u16* Cs_l  = Cs_h + 128 * 72;        // 36864 B (alias)

    const int tid = threadIdx.x;
    const int w = tid >> 6, lane = tid & 63;
    const int waveM = w & 1, waveN = w >> 1;
    const int quad = lane >> 4, l16 = lane & 15;

    const int xrow = tid >> 1, xko = (tid & 1) * 16;
    const int wrow = tid >> 2, wko = (tid & 3) * 8;

    const u16* xh_g  = Xh  + (size_t)(bm * 128 + xrow) * K + xko;
    const u16* xl_g  = Xl  + (size_t)(bm * 128 + xrow) * K + xko;
    const u16* w0h_g = W0h_ + (size_t)(bn * 64 + wrow) * K + wko;
    const u16* w0l_g = W0l_ + (size_t)(bn * 64 + wrow) * K + wko;
    const u16* w1h_g = W1h_ + (size_t)(bn * 64 + wrow) * K + wko;
    const u16* w1l_g = W1l_ + (size_t)(bn * 64 + wrow) * K + wko;

    f32x4 acc0[4][2] = {};
    f32x4 acc1[4][2] = {};

    for (int k0 = 0; k0 < K; k0 += 32) {
        uint4 xa = *(const uint4*)(xh_g + k0);
        uint4 xb = *(const uint4*)(xh_g + k0 + 8);
        uint4 xc = *(const uint4*)(xl_g + k0);
        uint4 xd = *(const uint4*)(xl_g + k0 + 8);
        uint4 w0a = *(const uint4*)(w0h_g + k0);
        uint4 w0c = *(const uint4*)(w0l_g + k0);
        uint4 w1a = *(const uint4*)(w1h_g + k0);
        uint4 w1c = *(const uint4*)(w1l_g + k0);
        __syncthreads();
        *(uint4*)&Xs_h[xrow * 40 + xko]     = xa;
        *(uint4*)&Xs_h[xrow * 40 + xko + 8] = xb;
        *(uint4*)&Xs_l[xrow * 40 + xko]     = xc;
        *(uint4*)&Xs_l[xrow * 40 + xko + 8] = xd;
        *(uint4*)&W0s_h[wrow * 40 + wko] = w0a;
        *(uint4*)&W0s_l[wrow * 40 + wko] = w0c;
        *(uint4*)&W1s_h[wrow * 40 + wko] = w1a;
        *(uint4*)&W1s_l[wrow * 40 + wko] = w1c;
        __syncthreads();

        short8 ah[4], al[4], b0h[2], b0l[2], b1h[2], b1l[2];
#pragma unroll
        for (int mt = 0; mt < 4; ++mt) {
            int r = (waveM * 64 + mt * 16 + l16) * 40 + quad * 8;
            ah[mt] = *(short8*)&Xs_h[r];
            al[mt] = *(short8*)&Xs_l[r];
        }
#pragma unroll
        for (int nt = 0; nt < 2; ++nt) {
            int r = (waveN * 32 + nt * 16 + l16) * 40 + quad * 8;
            b0h[nt] = *(short8*)&W0s_h[r];
            b0l[nt] = *(short8*)&W0s_l[r];
            b1h[nt] = *(short8*)&W1s_h[r];
            b1l[nt] = *(short8*)&W1s_l[r];
        }
#pragma unroll
        for (int mt = 0; mt < 4; ++mt)
#pragma unroll
            for (int nt = 0; nt < 2; ++nt) {
                acc0[mt][nt] = __builtin_amdgcn_mfma_f32_16x16x32_bf16(ah[mt], b0h[nt], acc0[mt][nt], 0, 0, 0);
                acc1[mt][nt] = __builtin_amdgcn_mfma_f32_16x16x32_bf16(ah[mt], b1h[nt], acc1[mt][nt], 0, 0, 0);
                acc0[mt][nt] = __builtin_amdgcn_mfma_f32_16x16x32_bf16(ah[mt], b0l[nt], acc0[mt][nt], 0, 0, 0);
                acc1[mt][nt] = __builtin_amdgcn_mfma_f32_16x16x32_bf16(ah[mt], b1l[nt], acc1[mt][nt], 0, 0, 0);
                acc0[mt][nt] = __builtin_amdgcn_mfma_f32_16x16x32_bf16(al[mt], b0h[nt], acc0[mt][nt], 0, 0, 0);
                acc1[mt][nt] = __builtin_amdgcn_mfma_f32_16x16x32_bf16(al[mt], b1h[nt], acc1[mt][nt], 0, 0, 0);
            }
    }

    const int bh = (bm >> 3) * H_ + bn;   // 8 m-blocks per batch; head = bn

    // ---- p1 epilogue (no LDS) ----
#pragma unroll
    for (int mt = 0; mt < 4; ++mt)
#pragma unroll
        for (int nt = 0; nt < 2; ++nt)
#pragma unroll
            for (int r = 0; r < 4; ++r) {
                int m = bm * 128 + waveM * 64 + mt * 16 + quad * 4 + r;
                int n = bn * 64 + waveN * 32 + nt * 16 + l16;
                float val = acc1[mt][nt][r] + bias1[n];
                int s = m & 1023, c = n & 63;
                size_t addr = ((size_t)bh * S_ + s) * 64 + c;
                u16 hh, ll; splitf(val, hh, ll);
                p1h[addr] = hh; p1l[addr] = ll;
            }

    // ---- q epilogue: q = (acc0 + b0) @ M_bh via split MFMA ----
    __syncthreads();
#pragma unroll
    for (int mt = 0; mt < 4; ++mt)
#pragma unroll
        for (int nt = 0; nt < 2; ++nt)
#pragma unroll
            for (int r = 0; r < 4; ++r) {
                int i = waveM * 64 + mt * 16 + quad * 4 + r;
                int a = waveN * 32 + nt * 16 + l16;
                float val = acc0[mt][nt][r] + bias0[bn * 64 + a];
                u16 hh, ll; splitf(val, hh, ll);
                Cs_h[i * 72 + a] = hh;
                Cs_l[i * 72 + a] = ll;
            }
    __syncthreads();

    const u16* MTh_b = MTh + (size_t)bh * 4096;
    const u16* MTl_b = MTl + (size_t)bh * 4096;
    f32x4 qacc[4][2] = {};
#pragma unroll
    for (int ch = 0; ch < 2; ++ch) {
        short8 mh[2], ml[2];
#pragma unroll
        for (int nt = 0; nt < 2; ++nt) {
            int c = waveN * 32 + nt * 16 + l16;
            mh[nt] = *(const short8*)&MTh_b[c * 64 + ch * 32 + quad * 8];
            ml[nt] = *(const short8*)&MTl_b[c * 64 + ch * 32 + quad * 8];
        }
#pragma unroll
        for (int mt = 0; mt < 4; ++mt) {
            int rr = (waveM * 64 + mt * 16 + l16) * 72 + ch * 32 + quad * 8;
            short8 ca = *(short8*)&Cs_h[rr];
            short8 cl = *(short8*)&Cs_l[rr];
#pragma unroll
            for (int nt = 0; nt < 2; ++nt) {
                qacc[mt][nt] = __builtin_amdgcn_mfma_f32_16x16x32_bf16(ca, mh[nt], qacc[mt][nt], 0, 0, 0);
                qacc[mt][nt] = __builtin_amdgcn_mfma_f32_16x16x32_bf16(ca, ml[nt], qacc[mt][nt], 0, 0, 0);
                qacc[mt][nt] = __builtin_amdgcn_mfma_f32_16x16x32_bf16(cl, mh[nt], qacc[mt][nt], 0, 0, 0);
            }
        }
    }
#pragma unroll
    for (int mt = 0; mt < 4; ++mt)
#pragma unroll
        for (int nt = 0; nt < 2; ++nt)
#pragma unroll
            for (int r = 0; r < 4; ++r) {
                int s = (bm & 7) * 128 + waveM * 64 + mt * 16 + quad * 4 + r;
                int c = waveN * 32 + nt * 16 + l16;
                size_t addr = ((size_t)bh * S_ + s) * 64 + c;
                u16 hh, ll; splitf(qacc[mt][nt][r], hh, ll);
                qh[addr] = hh; ql[addr] = ll;
            }
}

// ---------------------------------------------------------------------------
// plain bf16 GEMM body, 128x64 tile (verbatim R2, PASSING)
// ---------------------------------------------------------------------------
__device__ void plain128_body(
    const u16* __restrict__ Xb, const u16* __restrict__ Wb,
    const float* __restrict__ bias, u16* __restrict__ outB,
    float* __restrict__ outF, int mode, int bm, int bn, char* smem)
{
    const int K = 1024;
    u16* Xs = (u16*)smem;                // 128*40
    u16* Ws = Xs + 128 * 40;             // 64*40  (total 15360 B)

    const int tid = threadIdx.x;
    const int w = tid >> 6, lane = tid & 63;
    const int waveM = w & 1, waveN = w >> 1;
    const int quad = lane >> 4, l16 = lane & 15;
    const int xrow = tid >> 1, xko = (tid & 1) * 16;
    const int wrow = tid >> 2, wko = (tid & 3) * 8;

    const u16* xg = Xb + (size_t)(bm * 128 + xrow) * K + xko;
    const u16* wg = Wb + (size_t)(bn * 64 + wrow) * K + wko;

    f32x4 acc[4][2] = {};

    for (int k0 = 0; k0 < K; k0 += 32) {
        uint4 xa = *(const uint4*)(xg + k0);
        uint4 xb = *(const uint4*)(xg + k0 + 8);
        uint4 wa = *(const uint4*)(wg + k0);
        __syncthreads();
        *(uint4*)&Xs[xrow * 40 + xko]     = xa;
        *(uint4*)&Xs[xrow * 40 + xko + 8] = xb;
        *(uint4*)&Ws[wrow * 40 + wko]     = wa;
        __syncthreads();

        short8 af[4], bf_[2];
#pragma unroll
        for (int mt = 0; mt < 4; ++mt)
            af[mt] = *(short8*)&Xs[(waveM * 64 + mt * 16 + l16) * 40 + quad * 8];
#pragma unroll
        for (int nt = 0; nt < 2; ++nt)
            bf_[nt] = *(short8*)&Ws[(waveN * 32 + nt * 16 + l16) * 40 + quad * 8];
#pragma unroll
        for (int mt = 0; mt < 4; ++mt)
#pragma unroll
            for (int nt = 0; nt < 2; ++nt)
                acc[mt][nt] = __builtin_amdgcn_mfma_f32_16x16x32_bf16(af[mt], bf_[nt], acc[mt][nt], 0, 0, 0);
    }

#pragma unroll
    for (int mt = 0; mt < 4; ++mt)
#pragma unroll
        for (int nt = 0; nt < 2; ++nt)
#pragma unroll
            for (int r = 0; r < 4; ++r) {
                int m = bm * 128 + waveM * 64 + mt * 16 + quad * 4 + r;
                int n = bn * 64 + waveN * 32 + nt * 16 + l16;
                float val = acc[mt][nt][r] + bias[n];
                if (mode == 0) {
                    int b = m >> 10, s = m & 1023, h = n >> 6, c = n & 63;
                    outB[((size_t)((b * H_ + h) * 64 + c)) * S_ + s] = f2b(val);
                } else {
                    outF[(size_t)m * 1024 + n] = val;
                }
            }
}

// ---------------------------------------------------------------------------
// merged mid kernel (verbatim R2)
// ---------------------------------------------------------------------------
__global__ __launch_bounds__(256) void gemm_mid(
    const u16* __restrict__ xh, const u16* __restrict__ xl,
    const u16* __restrict__ w0h, const u16* __restrict__ w0l,
    const u16* __restrict__ w1h, const u16* __restrict__ w1l,
    const float* __restrict__ b0, const float* __restrict__ b1,
    const u16* __restrict__ MTh, const u16* __restrict__ MTl,
    u16* __restrict__ qh, u16* __restrict__ ql,
    u16* __restrict__ p1h, u16* __restrict__ p1l,
    const u16* __restrict__ wvb, const float* __restrict__ bv,
    u16* __restrict__ vT)
{
    __shared__ __align__(16) char smem[40960];
    int bid = blockIdx.x;
    if (bid < 512) {
        qp1_body(xh, xl, w0h, w0l, w1h, w1l, b0, b1, MTh, MTl,
                 qh, ql, p1h, p1l, bid & 31, bid >> 5, smem);
    } else {
        int b2 = bid - 512;
        plain128_body(xh, wvb, bv, vT, nullptr, 0, b2 & 31, b2 >> 5, smem);
    }
}

// final GEMM: out = values @ Wo^T + bo (fp32 out)
__global__ __launch_bounds__(256) void gemm_fin(
    const u16* __restrict__ values, const u16* __restrict__ wob,
    const float* __restrict__ bo, float* __restrict__ out)
{
    __shared__ __align__(16) char smem[15360];
    plain128_body(values, wob, bo, nullptr, out, 1, blockIdx.x, blockIdx.y, smem);
}

// ---------------------------------------------------------------------------
// FUSED logits+softmax+PV — HYBRID of R2 (fast QK) + R3 (barrier-free PV):
//  - q A-frags direct from global (R3-proven; loaded once, pre-loop)
//  - QK: R2's double-buffered LDS p1 staging, 1 barrier/iter (throughput-
//    proven; staging shares loads across waves and pipelines latency)
//  - softmax unchanged; redm/reds live at sm+36864 (untouched by QK bufs)
//  - P (32x1024 bf16) written ONCE to 64KB swizzled LDS (off ^= (row&7)<<4),
//    overwriting the dead QK/red buffers after a fence barrier
//  - PV: P from swizzled LDS (2-way reads = free), V direct from global
//    (L2-resident per bh), ZERO PV barriers
// Barriers: 26 (R2) -> 19. All MFMA sequences bitwise identical to R2/R3.
// ---------------------------------------------------------------------------
__global__ __launch_bounds__(512) void logits_softmax_pv(
    const u16* __restrict__ qh, const u16* __restrict__ ql,
    const u16* __restrict__ p1h, const u16* __restrict__ p1l,
    const u16* __restrict__ vT, float* __restrict__ attn,
    u16* __restrict__ values)
{
    int bh = blockIdx.x, i0 = blockIdx.y * 32;
    int b = bh >> 4, h = bh & 15;
    int tid = threadIdx.x, w = tid >> 6, lane = tid & 63;
    int quad = lane >> 4, l16 = lane & 15;
    int wg = w >> 2, wj = w & 3;

    __shared__ __align__(16) char sm[65536];
    u16* p1hs = (u16*)sm;                 // [2][64*72] = 18432 B
    u16* p1ls = (u16*)(sm + 18432);       // [2][64*72] -> 36864
    float* redm = (float*)(sm + 36864);   // [4][32] = 512 B
    float* reds = (float*)(sm + 37376);   // 512 B -> 37888
    // P phase alias: full sm[0,65536) = P [32 rows][2048 B] XOR-swizzled

    // ---- q A-frags direct from global ----
    short8 ah[2], al[2];
    {
        size_t gq = ((size_t)bh * S_ + i0 + wg * 16 + l16) * 64 + quad * 8;
        ah[0] = *(const short8*)&qh[gq];
        ah[1] = *(const short8*)&qh[gq + 32];
        al[0] = *(const short8*)&ql[gq];
        al[1] = *(const short8*)&ql[gq + 32];
    }

    // ---- QK: R2 double-buffered LDS staging ----
    const int jl = tid >> 3, c0s = (tid & 7) * 8;
    const size_t gp = ((size_t)bh * S_ + jl) * 64 + c0s;

    uint4 rha = *(const uint4*)&p1h[gp];
    uint4 rla = *(const uint4*)&p1l[gp];
    *(uint4*)&p1hs[jl * 72 + c0s] = rha;
    *(uint4*)&p1ls[jl * 72 + c0s] = rla;
    uint4 rh1 = *(const uint4*)&p1h[gp + 4096];
    uint4 rl1 = *(const uint4*)&p1l[gp + 4096];
    __syncthreads();    // buf0 visible

    f32x4 L[16];
    for (int t = 0; t < 16; ++t) {
        int cur = t & 1;
        uint4 rh2, rl2;
        if (t < 14) {
            size_t gn = gp + (size_t)(t + 2) * 4096;
            rh2 = *(const uint4*)&p1h[gn];
            rl2 = *(const uint4*)&p1l[gn];
        }
        int jr = wj * 16 + l16;
        const u16* Hb = &p1hs[cur * 4608 + jr * 72];
        const u16* Lb = &p1ls[cur * 4608 + jr * 72];
        short8 bh0 = *(const short8*)(Hb + quad * 8);
        short8 bh1 = *(const short8*)(Hb + 32 + quad * 8);
        short8 bl0 = *(const short8*)(Lb + quad * 8);
        short8 bl1 = *(const short8*)(Lb + 32 + quad * 8);
        f32x4 a = {};
        a = __builtin_amdgcn_mfma_f32_16x16x32_bf16(ah[0], bh0, a, 0, 0, 0);
        a = __builtin_amdgcn_mfma_f32_16x16x32_bf16(ah[1], bh1, a, 0, 0, 0);
        a = __builtin_amdgcn_mfma_f32_16x16x32_bf16(ah[0], bl0, a, 0, 0, 0);
        a = __builtin_amdgcn_mfma_f32_16x16x32_bf16(ah[1], bl1, a, 0, 0, 0);
        a = __builtin_amdgcn_mfma_f32_16x16x32_bf16(al[0], bh0, a, 0, 0, 0);
        a = __builtin_amdgcn_mfma_f32_16x16x32_bf16(al[1], bh1, a, 0, 0, 0);
        L[t] = a;
        if (t < 15) {
            *(uint4*)&p1hs[(1 - cur) * 4608 + jl * 72 + c0s] = rh1;
            *(uint4*)&p1ls[(1 - cur) * 4608 + jl * 72 + c0s] = rl1;
            if (t < 14) { rh1 = rh2; rl1 = rl2; }
            __syncthreads();
        }
    }

    // ---- softmax (structure unchanged) ----
    float mrow[4], srow[4];
#pragma unroll
    for (int r = 0; r < 4; ++r) {
        float m = L[0][r];
#pragma unroll
        for (int t = 1; t < 16; ++t) m = fmaxf(m, L[t][r]);
#pragma unroll
        for (int off = 1; off < 16; off <<= 1) m = fmaxf(m, __shfl_xor(m, off, 64));
        mrow[r] = m;
    }
    if (l16 == 0)
#pragma unroll
        for (int r = 0; r < 4; ++r) redm[wj * 32 + wg * 16 + quad * 4 + r] = mrow[r];
    __syncthreads();
#pragma unroll
    for (int r = 0; r < 4; ++r) {
        int rowg = wg * 16 + quad * 4 + r;
        float m = fmaxf(fmaxf(redm[0 * 32 + rowg], redm[1 * 32 + rowg]),
                        fmaxf(redm[2 * 32 + rowg], redm[3 * 32 + rowg]));
        float s = 0.f;
#pragma unroll
        for (int t = 0; t < 16; ++t) { L[t][r] = __expf(L[t][r] - m); s += L[t][r]; }
#pragma unroll
        for (int off = 1; off < 16; off <<= 1) s += __shfl_xor(s, off, 64);
        srow[r] = s;
    }
    if (l16 == 0)
#pragma unroll
        for (int r = 0; r < 4; ++r) reds[wj * 32 + wg * 16 + quad * 4 + r] = srow[r];
    __syncthreads();
#pragma unroll
    for (int r = 0; r < 4; ++r) {
        int rowg = wg * 16 + quad * 4 + r;
        float inv = 1.0f / (reds[0 * 32 + rowg] + reds[1 * 32 + rowg] +
                            reds[2 * 32 + rowg] + reds[3 * 32 + rowg]);
        float* arow = attn + ((size_t)bh * S_ + i0 + rowg) * S_;
#pragma unroll
        for (int t = 0; t < 16; ++t) {
            float p = L[t][r] * inv;
            L[t][r] = p;
            __builtin_nontemporal_store(p, &arow[t * 64 + wj * 16 + l16]);
        }
    }

    // ---- fence reds reads, then write whole P to swizzled LDS ----
    __syncthreads();
    {
        int row = wg * 16 + quad * 4;
        int colb = (wj * 16 + l16) * 2;
#pragma unroll
        for (int t = 0; t < 16; ++t)
#pragma unroll
            for (int r = 0; r < 4; ++r) {
                int off = (t * 128 + colb) ^ (((row + r) & 7) << 4);
                *(u16*)(sm + (row + r) * 2048 + off) = f2b(L[t][r]);
            }
    }
    __syncthreads();

    // ---- PV: P from swizzled LDS, V direct from global, barrier-free ----
    const int d = wj * 16 + l16;
    const int arow = wg * 16 + l16;
    const char* Pr = sm + arow * 2048;
    const int rxor = (arow & 7) << 4;
    const size_t gvb = (size_t)(bh * 64 + d) * S_ + quad * 8;
    f32x4 acc_pv = {};
#pragma unroll
    for (int t = 0; t < 16; ++t)
#pragma unroll
        for (int cc = 0; cc < 64; cc += 32) {
            short8 af = *(const short8*)(Pr + ((t * 128 + cc * 2 + quad * 16) ^ rxor));
            short8 bf = *(const short8*)&vT[gvb + t * 64 + cc];
            acc_pv = __builtin_amdgcn_mfma_f32_16x16x32_bf16(af, bf, acc_pv, 0, 0, 0);
        }
#pragma unroll
    for (int r = 0; r < 4; ++r) {
        int i = i0 + wg * 16 + quad * 4 + r;
        values[((size_t)(b * S_ + i)) * E_ + h * 64 + d] = f2b(acc_pv[r]);
    }
}

extern "C" void kernel_launch(void* const* d_in, const int* in_sizes, int n_in,
                              void* d_out, int out_size, void* d_ws, size_t ws_size,
                              hipStream_t stream)
{
    const float* x  = (const float*)d_in[0];
    const float* W0 = (const float*)d_in[1];
    const float* b0 = (const float*)d_in[2];
    const float* W1 = (const float*)d_in[3];
    const float* b1 = (const float*)d_in[4];
    const float* W2 = (const float*)d_in[5];
    const float* b2 = (const float*)d_in[6];
    const float* Wv = (const float*)d_in[7];
    const float* bv = (const float*)d_in[8];
    const float* Wo = (const float*)d_in[9];
    const float* bo = (const float*)d_in[10];
    const float* A  = (const float*)d_in[11];

    float* out  = (float*)d_out;
    float* attn = out + (size_t)B_ * S_ * E_;

    // workspace (~78.6 MB)
    u16* xh  = (u16*)d_ws;                  // 8 MB
    u16* xl  = xh + 4194304;                // 8 MB
    u16* w0h = xl + 4194304;                // 2 MB
    u16* w0l = w0h + 1048576;
    u16* w1h = w0l + 1048576;
    u16* w1l = w1h + 1048576;
    u16* p1h = w1l + 1048576;               // 8 MB
    u16* p1l = p1h + 4194304;               // 8 MB
    u16* qh  = p1l + 4194304;               // 8 MB
    u16* ql  = qh + 4194304;                // 8 MB
    u16* vT  = ql + 4194304;                // 8 MB (heads-transposed v)
    u16* values = vT + 4194304;             // 8 MB (bf16 natural)
    u16* MTh = values + 4194304;            // 512 KB (transposed M hi)
    u16* MTl = MTh + 262144;                // 512 KB
    u16* wob = MTl + 262144;                // 2 MB (bf16 Wo)
    // xsum partials [16][4][1024] fp32 = 256 KB — aliased onto p1h (written
    // by gemm_mid strictly after t2k_M consumed xsum_p).
    float* xsum_p = (float*)p1h;
    // wvb aliased onto values region: consumed by gemm_mid, which completes
    // before logits_softmax_pv writes values.
    u16* wvb = values;

    prep<<<8448, 256, 0, stream>>>(x, W0, W1, Wv, Wo, xsum_p,
                                   xh, xl, w0h, w0l, w1h, w1l, wvb, wob);
    t2k_M<<<dim3(16, 4), 256, 0, stream>>>(W2, b2, xsum_p, A, MTh, MTl);

    gemm_mid<<<1024, 256, 0, stream>>>(xh, xl, w0h, w0l, w1h, w1l,
                                       b0, b1, MTh, MTl, qh, ql, p1h, p1l,
                                       wvb, bv, vT);

    logits_softmax_pv<<<dim3(64, 32), 512, 0, stream>>>(qh, ql, p1h, p1l, vT, attn, values);

    gemm_fin<<<dim3(32, 16), 256, 0, stream>>>(values, wob, bo, out);
}

// Round 6
// 542.694 us; speedup vs baseline: 1.1930x; 1.0928x over previous
//
#include <hip/hip_runtime.h>
#include <hip/hip_bf16.h>
#include <cstddef>

#define B_ 4
#define S_ 1024
#define E_ 1024
#define H_ 16
#define D_ 64
#define BH_ (B_*H_)

typedef __attribute__((ext_vector_type(8))) short short8;    // 8 bf16
typedef __attribute__((ext_vector_type(4))) float f32x4;
typedef __attribute__((ext_vector_type(4))) unsigned short us4;
typedef unsigned short u16;

__device__ inline u16 f2b(float x) {
    return __builtin_bit_cast(u16, __float2bfloat16(x));
}
__device__ inline float b2f(u16 u) {
    return __bfloat162float(__builtin_bit_cast(__hip_bfloat16, u));
}
__device__ inline void splitf(float x, u16& h, u16& l) {
    h = f2b(x); l = f2b(x - b2f(h));
}

__device__ inline void split_one(const float* __restrict__ in,
                                 u16* __restrict__ oh, u16* __restrict__ ol, int i)
{
    float4 v = ((const float4*)in)[i];
    us4 h, l;
    splitf(v.x, ((u16*)&h)[0], ((u16*)&l)[0]);
    splitf(v.y, ((u16*)&h)[1], ((u16*)&l)[1]);
    splitf(v.z, ((u16*)&h)[2], ((u16*)&l)[2]);
    splitf(v.w, ((u16*)&h)[3], ((u16*)&l)[3]);
    ((us4*)oh)[i] = h;
    ((us4*)ol)[i] = l;
}

__device__ inline void conv_one(const float* __restrict__ in,
                                u16* __restrict__ ob, int i)
{
    float4 v = ((const float4*)in)[i];
    us4 h;
    ((u16*)&h)[0] = f2b(v.x); ((u16*)&h)[1] = f2b(v.y);
    ((u16*)&h)[2] = f2b(v.z); ((u16*)&h)[3] = f2b(v.w);
    ((us4*)ob)[i] = h;
}

// ---------------------------------------------------------------------------
// Fused prep (unchanged, PASSING)
// ---------------------------------------------------------------------------
__global__ __launch_bounds__(256) void prep(
    const float* __restrict__ x, const float* __restrict__ W0,
    const float* __restrict__ W1, const float* __restrict__ Wv,
    const float* __restrict__ Wo, float* __restrict__ xsum_p,
    u16* __restrict__ xh, u16* __restrict__ xl,
    u16* __restrict__ w0h, u16* __restrict__ w0l,
    u16* __restrict__ w1h, u16* __restrict__ w1l,
    u16* __restrict__ wvb, u16* __restrict__ wob)
{
    int bid = blockIdx.x, tid = threadIdx.x;
    if (bid < 4096) {
        split_one(x, xh, xl, bid * 256 + tid);
    } else if (bid < 5120) {
        split_one(W0, w0h, w0l, (bid - 4096) * 256 + tid);
    } else if (bid < 6144) {
        split_one(W1, w1h, w1l, (bid - 5120) * 256 + tid);
    } else if (bid < 7168) {
        conv_one(Wv, wvb, (bid - 6144) * 256 + tid);
    } else if (bid < 8192) {
        conv_one(Wo, wob, (bid - 7168) * 256 + tid);
    } else {
        int p = bid - 8192;                 // [0,256)
        int kb = p & 3, b = (p >> 2) & 3, ch = p >> 4;
        int k = kb * 256 + tid;
        const float* base = x + ((size_t)(b * S_ + ch * 64)) * E_ + k;
        float s = 0.f;
#pragma unroll 8
        for (int j = 0; j < 64; ++j) s += base[(size_t)j * E_];
        xsum_p[(ch * 4 + b) * E_ + k] = s;
    }
}

// ---------------------------------------------------------------------------
// Fused t2 + M (unchanged, PASSING)
// ---------------------------------------------------------------------------
__global__ __launch_bounds__(256) void t2k_M(
    const float* __restrict__ W2, const float* __restrict__ b2v,
    const float* __restrict__ xsum_p, const float* __restrict__ A,
    u16* __restrict__ MTh, u16* __restrict__ MTl)
{
    int h = blockIdx.x, b = blockIdx.y, tid = threadIdx.x;
    __shared__ float xs[1024];
    __shared__ float t2s[64];

#pragma unroll
    for (int j = 0; j < 4; ++j) {
        int k = j * 256 + tid;
        float s = 0.f;
#pragma unroll
        for (int c = 0; c < 16; ++c) s += xsum_p[(c * 4 + b) * E_ + k];
        xs[k] = s;
    }
    __syncthreads();

    int w = tid >> 6, lane = tid & 63;
    for (int nn = w; nn < 64; nn += 4) {
        int n = h * 64 + nn;
        const float* wr = W2 + (size_t)n * E_;
        float s = 0.f;
#pragma unroll
        for (int t = 0; t < 16; ++t) s = fmaf(wr[t * 64 + lane], xs[t * 64 + lane], s);
#pragma unroll
        for (int off = 1; off < 64; off <<= 1) s += __shfl_xor(s, off, 64);
        if (lane == 0) t2s[nn] = s + 1024.0f * b2v[n];
    }
    __syncthreads();

    int bh = b * H_ + h;
    int c = tid & 63;
    int a0 = (tid >> 6) * 16;
    for (int a = a0; a < a0 + 16; ++a) {
        float s = 0.f;
        const float* Ap = A + ((size_t)a * 64 + c) * 64;
#pragma unroll 8
        for (int d = 0; d < 64; ++d) s = fmaf(Ap[d], t2s[d], s);
        u16 hh, ll; splitf(s * 0.125f, hh, ll);
        MTh[(size_t)bh * 4096 + c * 64 + a] = hh;
        MTl[(size_t)bh * 4096 + c * 64 + a] = ll;
    }
}

// ---------------------------------------------------------------------------
// qp1 body: split GEMM 128x64 (verbatim R2, PASSING)
// ---------------------------------------------------------------------------
__device__ void qp1_body(
    const u16* __restrict__ Xh, const u16* __restrict__ Xl,
    const u16* __restrict__ W0h_, const u16* __restrict__ W0l_,
    const u16* __restrict__ W1h_, const u16* __restrict__ W1l_,
    const float* __restrict__ bias0, const float* __restrict__ bias1,
    const u16* __restrict__ MTh, const u16* __restrict__ MTl,
    u16* __restrict__ qh, u16* __restrict__ ql,
    u16* __restrict__ p1h, u16* __restrict__ p1l,
    int bm, int bn, char* smem)
{
    const int K = 1024;
    u16* Xs_h  = (u16*)smem;             // 128*40
    u16* Xs_l  = Xs_h + 128 * 40;
    u16* W0s_h = Xs_l + 128 * 40;        // 64*40 each
    u16* W0s_l = W0s_h + 64 * 40;
    u16* W1s_h = W0s_l + 64 * 40;
    u16* W1s_l = W1s_h + 64 * 40;        // staging total 40960 B
    u16* Cs_h  = (u16*)smem;             // epilogue: 128*72
    u16* Cs_l  = Cs_h + 128 * 72;        // 36864 B (alias)

    const int tid = threadIdx.x;
    const int w = tid >> 6, lane = tid & 63;
    const int waveM = w & 1, waveN = w >> 1;
    const int quad = lane >> 4, l16 = lane & 15;

    const int xrow = tid >> 1, xko = (tid & 1) * 16;
    const int wrow = tid >> 2, wko = (tid & 3) * 8;

    const u16* xh_g  = Xh  + (size_t)(bm * 128 + xrow) * K + xko;
    const u16* xl_g  = Xl  + (size_t)(bm * 128 + xrow) * K + xko;
    const u16* w0h_g = W0h_ + (size_t)(bn * 64 + wrow) * K + wko;
    const u16* w0l_g = W0l_ + (size_t)(bn * 64 + wrow) * K + wko;
    const u16* w1h_g = W1h_ + (size_t)(bn * 64 + wrow) * K + wko;
    const u16* w1l_g = W1l_ + (size_t)(bn * 64 + wrow) * K + wko;

    f32x4 acc0[4][2] = {};
    f32x4 acc1[4][2] = {};

    for (int k0 = 0; k0 < K; k0 += 32) {
        uint4 xa = *(const uint4*)(xh_g + k0);
        uint4 xb = *(const uint4*)(xh_g + k0 + 8);
        uint4 xc = *(const uint4*)(xl_g + k0);
        uint4 xd = *(const uint4*)(xl_g + k0 + 8);
        uint4 w0a = *(const uint4*)(w0h_g + k0);
        uint4 w0c = *(const uint4*)(w0l_g + k0);
        uint4 w1a = *(const uint4*)(w1h_g + k0);
        uint4 w1c = *(const uint4*)(w1l_g + k0);
        __syncthreads();
        *(uint4*)&Xs_h[xrow * 40 + xko]     = xa;
        *(uint4*)&Xs_h[xrow * 40 + xko + 8] = xb;
        *(uint4*)&Xs_l[xrow * 40 + xko]     = xc;
        *(uint4*)&Xs_l[xrow * 40 + xko + 8] = xd;
        *(uint4*)&W0s_h[wrow * 40 + wko] = w0a;
        *(uint4*)&W0s_l[wrow * 40 + wko] = w0c;
        *(uint4*)&W1s_h[wrow * 40 + wko] = w1a;
        *(uint4*)&W1s_l[wrow * 40 + wko] = w1c;
        __syncthreads();

        short8 ah[4], al[4], b0h[2], b0l[2], b1h[2], b1l[2];
#pragma unroll
        for (int mt = 0; mt < 4; ++mt) {
            int r = (waveM * 64 + mt * 16 + l16) * 40 + quad * 8;
            ah[mt] = *(short8*)&Xs_h[r];
            al[mt] = *(short8*)&Xs_l[r];
        }
#pragma unroll
        for (int nt = 0; nt < 2; ++nt) {
            int r = (waveN * 32 + nt * 16 + l16) * 40 + quad * 8;
            b0h[nt] = *(short8*)&W0s_h[r];
            b0l[nt] = *(short8*)&W0s_l[r];
            b1h[nt] = *(short8*)&W1s_h[r];
            b1l[nt] = *(short8*)&W1s_l[r];
        }
#pragma unroll
        for (int mt = 0; mt < 4; ++mt)
#pragma unroll
            for (int nt = 0; nt < 2; ++nt) {
                acc0[mt][nt] = __builtin_amdgcn_mfma_f32_16x16x32_bf16(ah[mt], b0h[nt], acc0[mt][nt], 0, 0, 0);
                acc1[mt][nt] = __builtin_amdgcn_mfma_f32_16x16x32_bf16(ah[mt], b1h[nt], acc1[mt][nt], 0, 0, 0);
                acc0[mt][nt] = __builtin_amdgcn_mfma_f32_16x16x32_bf16(ah[mt], b0l[nt], acc0[mt][nt], 0, 0, 0);
                acc1[mt][nt] = __builtin_amdgcn_mfma_f32_16x16x32_bf16(ah[mt], b1l[nt], acc1[mt][nt], 0, 0, 0);
                acc0[mt][nt] = __builtin_amdgcn_mfma_f32_16x16x32_bf16(al[mt], b0h[nt], acc0[mt][nt], 0, 0, 0);
                acc1[mt][nt] = __builtin_amdgcn_mfma_f32_16x16x32_bf16(al[mt], b1h[nt], acc1[mt][nt], 0, 0, 0);
            }
    }

    const int bh = (bm >> 3) * H_ + bn;   // 8 m-blocks per batch; head = bn

    // ---- p1 epilogue (no LDS) ----
#pragma unroll
    for (int mt = 0; mt < 4; ++mt)
#pragma unroll
        for (int nt = 0; nt < 2; ++nt)
#pragma unroll
            for (int r = 0; r < 4; ++r) {
                int m = bm * 128 + waveM * 64 + mt * 16 + quad * 4 + r;
                int n = bn * 64 + waveN * 32 + nt * 16 + l16;
                float val = acc1[mt][nt][r] + bias1[n];
                int s = m & 1023, c = n & 63;
                size_t addr = ((size_t)bh * S_ + s) * 64 + c;
                u16 hh, ll; splitf(val, hh, ll);
                p1h[addr] = hh; p1l[addr] = ll;
            }

    // ---- q epilogue: q = (acc0 + b0) @ M_bh via split MFMA ----
    __syncthreads();
#pragma unroll
    for (int mt = 0; mt < 4; ++mt)
#pragma unroll
        for (int nt = 0; nt < 2; ++nt)
#pragma unroll
            for (int r = 0; r < 4; ++r) {
                int i = waveM * 64 + mt * 16 + quad * 4 + r;
                int a = waveN * 32 + nt * 16 + l16;
                float val = acc0[mt][nt][r] + bias0[bn * 64 + a];
                u16 hh, ll; splitf(val, hh, ll);
                Cs_h[i * 72 + a] = hh;
                Cs_l[i * 72 + a] = ll;
            }
    __syncthreads();

    const u16* MTh_b = MTh + (size_t)bh * 4096;
    const u16* MTl_b = MTl + (size_t)bh * 4096;
    f32x4 qacc[4][2] = {};
#pragma unroll
    for (int ch = 0; ch < 2; ++ch) {
        short8 mh[2], ml[2];
#pragma unroll
        for (int nt = 0; nt < 2; ++nt) {
            int c = waveN * 32 + nt * 16 + l16;
            mh[nt] = *(const short8*)&MTh_b[c * 64 + ch * 32 + quad * 8];
            ml[nt] = *(const short8*)&MTl_b[c * 64 + ch * 32 + quad * 8];
        }
#pragma unroll
        for (int mt = 0; mt < 4; ++mt) {
            int rr = (waveM * 64 + mt * 16 + l16) * 72 + ch * 32 + quad * 8;
            short8 ca = *(short8*)&Cs_h[rr];
            short8 cl = *(short8*)&Cs_l[rr];
#pragma unroll
            for (int nt = 0; nt < 2; ++nt) {
                qacc[mt][nt] = __builtin_amdgcn_mfma_f32_16x16x32_bf16(ca, mh[nt], qacc[mt][nt], 0, 0, 0);
                qacc[mt][nt] = __builtin_amdgcn_mfma_f32_16x16x32_bf16(ca, ml[nt], qacc[mt][nt], 0, 0, 0);
                qacc[mt][nt] = __builtin_amdgcn_mfma_f32_16x16x32_bf16(cl, mh[nt], qacc[mt][nt], 0, 0, 0);
            }
        }
    }
#pragma unroll
    for (int mt = 0; mt < 4; ++mt)
#pragma unroll
        for (int nt = 0; nt < 2; ++nt)
#pragma unroll
            for (int r = 0; r < 4; ++r) {
                int s = (bm & 7) * 128 + waveM * 64 + mt * 16 + quad * 4 + r;
                int c = waveN * 32 + nt * 16 + l16;
                size_t addr = ((size_t)bh * S_ + s) * 64 + c;
                u16 hh, ll; splitf(qacc[mt][nt][r], hh, ll);
                qh[addr] = hh; ql[addr] = ll;
            }
}

// ---------------------------------------------------------------------------
// plain bf16 GEMM body, 128x128 tile: 16 MFMA/wave per k-step between 2
// barriers, half the W-panel re-staging vs 128x64. K-order per output
// identical -> bitwise-identical results.
// mode 0: bf16 transposed heads layout vT[(bh*64+d)*S + s]
// mode 1: fp32 natural out
// REQUIRES: bm in [0, M/128), bn in [0, 8)  (N = 1024)
// ---------------------------------------------------------------------------
__device__ void plain128_body(
    const u16* __restrict__ Xb, const u16* __restrict__ Wb,
    const float* __restrict__ bias, u16* __restrict__ outB,
    float* __restrict__ outF, int mode, int bm, int bn, char* smem)
{
    const int K = 1024;
    u16* Xs = (u16*)smem;                // 128*40
    u16* Ws = Xs + 128 * 40;             // 128*40  (total 20480 B)

    const int tid = threadIdx.x;
    const int w = tid >> 6, lane = tid & 63;
    const int waveM = w & 1, waveN = w >> 1;
    const int quad = lane >> 4, l16 = lane & 15;
    const int row = tid >> 1, ko = (tid & 1) * 16;

    const u16* xg = Xb + (size_t)(bm * 128 + row) * K + ko;
    const u16* wg = Wb + (size_t)(bn * 128 + row) * K + ko;

    f32x4 acc[4][4] = {};

    for (int k0 = 0; k0 < K; k0 += 32) {
        uint4 xa = *(const uint4*)(xg + k0);
        uint4 xb = *(const uint4*)(xg + k0 + 8);
        uint4 wa = *(const uint4*)(wg + k0);
        uint4 wb = *(const uint4*)(wg + k0 + 8);
        __syncthreads();
        *(uint4*)&Xs[row * 40 + ko]     = xa;
        *(uint4*)&Xs[row * 40 + ko + 8] = xb;
        *(uint4*)&Ws[row * 40 + ko]     = wa;
        *(uint4*)&Ws[row * 40 + ko + 8] = wb;
        __syncthreads();

        short8 af[4], bf_[4];
#pragma unroll
        for (int mt = 0; mt < 4; ++mt)
            af[mt] = *(short8*)&Xs[(waveM * 64 + mt * 16 + l16) * 40 + quad * 8];
#pragma unroll
        for (int nt = 0; nt < 4; ++nt)
            bf_[nt] = *(short8*)&Ws[(waveN * 64 + nt * 16 + l16) * 40 + quad * 8];
#pragma unroll
        for (int mt = 0; mt < 4; ++mt)
#pragma unroll
            for (int nt = 0; nt < 4; ++nt)
                acc[mt][nt] = __builtin_amdgcn_mfma_f32_16x16x32_bf16(af[mt], bf_[nt], acc[mt][nt], 0, 0, 0);
    }

#pragma unroll
    for (int mt = 0; mt < 4; ++mt)
#pragma unroll
        for (int nt = 0; nt < 4; ++nt)
#pragma unroll
            for (int r = 0; r < 4; ++r) {
                int m = bm * 128 + waveM * 64 + mt * 16 + quad * 4 + r;
                int n = bn * 128 + waveN * 64 + nt * 16 + l16;
                float val = acc[mt][nt][r] + bias[n];
                if (mode == 0) {
                    int b = m >> 10, s = m & 1023, h = n >> 6, c = n & 63;
                    outB[((size_t)((b * H_ + h) * 64 + c)) * S_ + s] = f2b(val);
                } else {
                    outF[(size_t)m * 1024 + n] = val;
                }
            }
}

// ---------------------------------------------------------------------------
// merged mid kernel: blocks [0,512) qp1, [512,768) vT gemm (128x128 tiles)
// ---------------------------------------------------------------------------
__global__ __launch_bounds__(256) void gemm_mid(
    const u16* __restrict__ xh, const u16* __restrict__ xl,
    const u16* __restrict__ w0h, const u16* __restrict__ w0l,
    const u16* __restrict__ w1h, const u16* __restrict__ w1l,
    const float* __restrict__ b0, const float* __restrict__ b1,
    const u16* __restrict__ MTh, const u16* __restrict__ MTl,
    u16* __restrict__ qh, u16* __restrict__ ql,
    u16* __restrict__ p1h, u16* __restrict__ p1l,
    const u16* __restrict__ wvb, const float* __restrict__ bv,
    u16* __restrict__ vT)
{
    __shared__ __align__(16) char smem[40960];
    int bid = blockIdx.x;
    if (bid < 512) {
        qp1_body(xh, xl, w0h, w0l, w1h, w1l, b0, b1, MTh, MTl,
                 qh, ql, p1h, p1l, bid & 31, bid >> 5, smem);
    } else {
        int b2 = bid - 512;                 // [0,256): bm = b2&31 in [0,32), bn = b2>>5 in [0,8)
        plain128_body(xh, wvb, bv, vT, nullptr, 0, b2 & 31, b2 >> 5, smem);
    }
}

// final GEMM: out = values @ Wo^T + bo (fp32 out), 128x128 tiles
// grid MUST be dim3(32, 8): bm = blockIdx.x in [0,32), bn = blockIdx.y in [0,8)
__global__ __launch_bounds__(256) void gemm_fin(
    const u16* __restrict__ values, const u16* __restrict__ wob,
    const float* __restrict__ bo, float* __restrict__ out)
{
    __shared__ __align__(16) char smem[20480];
    plain128_body(values, wob, bo, nullptr, out, 1, blockIdx.x, blockIdx.y, smem);
}

// ---------------------------------------------------------------------------
// FUSED logits+softmax+PV — VERBATIM R2 (537 us state, PASSING, fast).
// QK double-buffered (1 barrier/iter); PV 2 KV-tiles per barrier.
// ---------------------------------------------------------------------------
__global__ __launch_bounds__(512) void logits_softmax_pv(
    const u16* __restrict__ qh, const u16* __restrict__ ql,
    const u16* __restrict__ p1h, const u16* __restrict__ p1l,
    const u16* __restrict__ vT, float* __restrict__ attn,
    u16* __restrict__ values)
{
    int bh = blockIdx.x, i0 = blockIdx.y * 32;
    int b = bh >> 4, h = bh & 15;
    int tid = threadIdx.x, w = tid >> 6, lane = tid & 63;
    int quad = lane >> 4, l16 = lane & 15;
    int wg = w >> 2, wj = w & 3;

    __shared__ __align__(16) char sm[56320];
    u16* qhs  = (u16*)sm;                 // 32*72 u16 = 4608 B
    u16* qls  = (u16*)(sm + 4608);
    u16* p1hs = (u16*)(sm + 9216);        // [2][64*72] = 18432 B
    u16* p1ls = (u16*)(sm + 27648);       // [2][64*72] = 18432 B -> 46080
    float* redm = (float*)(sm + 55296);   // [4][32] = 512 B
    float* reds = (float*)(sm + 55808);   // 512 B -> 56320
    // PV-phase aliases (q + p1 staging dead after QK/softmax barriers):
    u16* Ps  = (u16*)sm;                  // [2][2][32*72] = 18432 B
    u16* vs_ = (u16*)(sm + 18432);        // [2][2][64*72] = 36864 B -> 55296

    {   // stage q (32x64 hi/lo)
        int row = tid >> 4, c0 = (tid & 15) * 4;
        size_t g = ((size_t)bh * S_ + i0 + row) * 64 + c0;
        *(us4*)&qhs[row * 72 + c0] = *(const us4*)&qh[g];
        *(us4*)&qls[row * 72 + c0] = *(const us4*)&ql[g];
    }

    // p1 staging: thread covers (row jl, 8 cols) — tile stride 4096 elems
    const int jl = tid >> 3, c0s = (tid & 7) * 8;
    const size_t gp = ((size_t)bh * S_ + jl) * 64 + c0s;

    uint4 rha = *(const uint4*)&p1h[gp];
    uint4 rla = *(const uint4*)&p1l[gp];
    *(uint4*)&p1hs[jl * 72 + c0s] = rha;
    *(uint4*)&p1ls[jl * 72 + c0s] = rla;
    uint4 rh1 = *(const uint4*)&p1h[gp + 4096];
    uint4 rl1 = *(const uint4*)&p1l[gp + 4096];
    __syncthreads();    // q + buf0 visible

    short8 ah[2], al[2];
#pragma unroll
    for (int ch = 0; ch < 2; ++ch) {
        ah[ch] = *(short8*)&qhs[(wg * 16 + l16) * 72 + ch * 32 + quad * 8];
        al[ch] = *(short8*)&qls[(wg * 16 + l16) * 72 + ch * 32 + quad * 8];
    }

    f32x4 L[16];
    for (int t = 0; t < 16; ++t) {
        int cur = t & 1;
        uint4 rh2, rl2;
        if (t < 14) {
            size_t gn = gp + (size_t)(t + 2) * 4096;
            rh2 = *(const uint4*)&p1h[gn];
            rl2 = *(const uint4*)&p1l[gn];
        }
        int jr = wj * 16 + l16;
        const u16* Hb = &p1hs[cur * 4608 + jr * 72];
        const u16* Lb = &p1ls[cur * 4608 + jr * 72];
        short8 bh0 = *(const short8*)(Hb + quad * 8);
        short8 bh1 = *(const short8*)(Hb + 32 + quad * 8);
        short8 bl0 = *(const short8*)(Lb + quad * 8);
        short8 bl1 = *(const short8*)(Lb + 32 + quad * 8);
        f32x4 a = {};
        a = __builtin_amdgcn_mfma_f32_16x16x32_bf16(ah[0], bh0, a, 0, 0, 0);
        a = __builtin_amdgcn_mfma_f32_16x16x32_bf16(ah[1], bh1, a, 0, 0, 0);
        a = __builtin_amdgcn_mfma_f32_16x16x32_bf16(ah[0], bl0, a, 0, 0, 0);
        a = __builtin_amdgcn_mfma_f32_16x16x32_bf16(ah[1], bl1, a, 0, 0, 0);
        a = __builtin_amdgcn_mfma_f32_16x16x32_bf16(al[0], bh0, a, 0, 0, 0);
        a = __builtin_amdgcn_mfma_f32_16x16x32_bf16(al[1], bh1, a, 0, 0, 0);
        L[t] = a;
        if (t < 15) {
            *(uint4*)&p1hs[(1 - cur) * 4608 + jl * 72 + c0s] = rh1;
            *(uint4*)&p1ls[(1 - cur) * 4608 + jl * 72 + c0s] = rl1;
            if (t < 14) { rh1 = rh2; rl1 = rl2; }
            __syncthreads();
        }
    }

    // softmax
    float mrow[4], srow[4];
#pragma unroll
    for (int r = 0; r < 4; ++r) {
        float m = L[0][r];
#pragma unroll
        for (int t = 1; t < 16; ++t) m = fmaxf(m, L[t][r]);
#pragma unroll
        for (int off = 1; off < 16; off <<= 1) m = fmaxf(m, __shfl_xor(m, off, 64));
        mrow[r] = m;
    }
    if (l16 == 0)
#pragma unroll
        for (int r = 0; r < 4; ++r) redm[wj * 32 + wg * 16 + quad * 4 + r] = mrow[r];
    __syncthreads();
#pragma unroll
    for (int r = 0; r < 4; ++r) {
        int rowg = wg * 16 + quad * 4 + r;
        float m = fmaxf(fmaxf(redm[0 * 32 + rowg], redm[1 * 32 + rowg]),
                        fmaxf(redm[2 * 32 + rowg], redm[3 * 32 + rowg]));
        float s = 0.f;
#pragma unroll
        for (int t = 0; t < 16; ++t) { L[t][r] = __expf(L[t][r] - m); s += L[t][r]; }
#pragma unroll
        for (int off = 1; off < 16; off <<= 1) s += __shfl_xor(s, off, 64);
        srow[r] = s;
    }
    if (l16 == 0)
#pragma unroll
        for (int r = 0; r < 4; ++r) reds[wj * 32 + wg * 16 + quad * 4 + r] = srow[r];
    __syncthreads();
#pragma unroll
    for (int r = 0; r < 4; ++r) {
        int rowg = wg * 16 + quad * 4 + r;
        float inv = 1.0f / (reds[0 * 32 + rowg] + reds[1 * 32 + rowg] +
                            reds[2 * 32 + rowg] + reds[3 * 32 + rowg]);
        float* arow = attn + ((size_t)bh * S_ + i0 + rowg) * S_;
#pragma unroll
        for (int t = 0; t < 16; ++t) {
            float p = L[t][r] * inv;
            L[t][r] = p;
            __builtin_nontemporal_store(p, &arow[t * 64 + wj * 16 + l16]);
        }
    }

    // ---- PV (2 KV-tiles per barrier, double-buffered) ----
    const int dv = tid >> 3, jc = (tid & 7) * 8;
    const size_t gv = (size_t)(bh * 64 + dv) * S_;
    uint4 rv0 = *(const uint4*)&vT[gv + jc];
    uint4 rv1 = *(const uint4*)&vT[gv + 64 + jc];

    f32x4 acc_pv = {};
    const int d = wj * 16 + l16;
    for (int tt = 0; tt < 8; ++tt) {
        int cur = tt & 1;
        u16* Pb = Ps + cur * 4608;          // [2t][32*72]
        u16* Vb = vs_ + cur * 9216;         // [2t][64*72]
#pragma unroll
        for (int r = 0; r < 4; ++r) {
            int pr = (wg * 16 + quad * 4 + r) * 72 + wj * 16 + l16;
            Pb[pr]        = f2b(L[2 * tt][r]);
            Pb[2304 + pr] = f2b(L[2 * tt + 1][r]);
        }
        *(uint4*)&Vb[dv * 72 + jc]        = rv0;
        *(uint4*)&Vb[4608 + dv * 72 + jc] = rv1;
        __syncthreads();
        if (tt < 7) {
            rv0 = *(const uint4*)&vT[gv + (size_t)(2 * tt + 2) * 64 + jc];
            rv1 = *(const uint4*)&vT[gv + (size_t)(2 * tt + 3) * 64 + jc];
        }
#pragma unroll
        for (int tp = 0; tp < 2; ++tp)
#pragma unroll
            for (int cc = 0; cc < 64; cc += 32) {
                short8 af = *(short8*)&Pb[tp * 2304 + (wg * 16 + l16) * 72 + cc + quad * 8];
                short8 bf = *(short8*)&vs_[cur * 9216 + tp * 4608 + d * 72 + cc + quad * 8];
                acc_pv = __builtin_amdgcn_mfma_f32_16x16x32_bf16(af, bf, acc_pv, 0, 0, 0);
            }
    }
#pragma unroll
    for (int r = 0; r < 4; ++r) {
        int i = i0 + wg * 16 + quad * 4 + r;
        values[((size_t)(b * S_ + i)) * E_ + h * 64 + d] = f2b(acc_pv[r]);
    }
}

extern "C" void kernel_launch(void* const* d_in, const int* in_sizes, int n_in,
                              void* d_out, int out_size, void* d_ws, size_t ws_size,
                              hipStream_t stream)
{
    const float* x  = (const float*)d_in[0];
    const float* W0 = (const float*)d_in[1];
    const float* b0 = (const float*)d_in[2];
    const float* W1 = (const float*)d_in[3];
    const float* b1 = (const float*)d_in[4];
    const float* W2 = (const float*)d_in[5];
    const float* b2 = (const float*)d_in[6];
    const float* Wv = (const float*)d_in[7];
    const float* bv = (const float*)d_in[8];
    const float* Wo = (const float*)d_in[9];
    const float* bo = (const float*)d_in[10];
    const float* A  = (const float*)d_in[11];

    float* out  = (float*)d_out;
    float* attn = out + (size_t)B_ * S_ * E_;

    // workspace (~78.6 MB)
    u16* xh  = (u16*)d_ws;                  // 8 MB
    u16* xl  = xh + 4194304;                // 8 MB
    u16* w0h = xl + 4194304;                // 2 MB
    u16* w0l = w0h + 1048576;
    u16* w1h = w0l + 1048576;
    u16* w1l = w1h + 1048576;
    u16* p1h = w1l + 1048576;               // 8 MB
    u16* p1l = p1h + 4194304;               // 8 MB
    u16* qh  = p1l + 4194304;               // 8 MB
    u16* ql  = qh + 4194304;                // 8 MB
    u16* vT  = ql + 4194304;                // 8 MB (heads-transposed v)
    u16* values = vT + 4194304;             // 8 MB (bf16 natural)
    u16* MTh = values + 4194304;            // 512 KB (transposed M hi)
    u16* MTl = MTh + 262144;                // 512 KB
    u16* wob = MTl + 262144;                // 2 MB (bf16 Wo)
    // xsum partials [16][4][1024] fp32 = 256 KB — aliased onto p1h (written
    // by gemm_mid strictly after t2k_M consumed xsum_p).
    float* xsum_p = (float*)p1h;
    // wvb aliased onto values region: consumed by gemm_mid, which completes
    // before logits_softmax_pv writes values.
    u16* wvb = values;

    prep<<<8448, 256, 0, stream>>>(x, W0, W1, Wv, Wo, xsum_p,
                                   xh, xl, w0h, w0l, w1h, w1l, wvb, wob);
    t2k_M<<<dim3(16, 4), 256, 0, stream>>>(W2, b2, xsum_p, A, MTh, MTl);

    gemm_mid<<<768, 256, 0, stream>>>(xh, xl, w0h, w0l, w1h, w1l,
                                      b0, b1, MTh, MTl, qh, ql, p1h, p1l,
                                      wvb, bv, vT);

    logits_softmax_pv<<<dim3(64, 32), 512, 0, stream>>>(qh, ql, p1h, p1l, vT, attn, values);

    gemm_fin<<<dim3(32, 8), 256, 0, stream>>>(values, wob, bo, out);
}